// Round 1
// baseline (894.634 us; speedup 1.0000x reference)
//
#include <hip/hip_runtime.h>
#include <math.h>

// ConceptBank: B=4, R=64, D=768, KEY_DIM=128, N_KEYS=500, TOPK=4
// Key insight: scores[i*500+j] = row_s[i] + col_s[j]  =>  global top-4 is a
// subset of {top4 rows} x {top4 cols} (16 candidates).
//
// One block per (b,r) register: 256 blocks x 256 threads.

constexpr int DD    = 768;
constexpr int KD    = 128;
constexpr int HALF  = 64;
constexpr int NKEYS = 500;
constexpr int NREG  = 256;   // B*R
constexpr int TK    = 4;

__global__ __launch_bounds__(256) void concept_all(
    const float* __restrict__ registers,  // 256*768
    const float* __restrict__ row_keys,   // 500*64
    const float* __restrict__ col_keys,   // 500*64
    const float* __restrict__ concepts,   // 250000*768
    const float* __restrict__ ln_gamma,   // 768
    const float* __restrict__ ln_beta,    // 768
    const float* __restrict__ Wq,         // 768*128
    const float* __restrict__ bq,         // 128
    const float* __restrict__ Wqc,        // 128*768
    const float* __restrict__ bqc,        // 768
    float* __restrict__ out)              // concatenated outputs
{
    const int row = blockIdx.x;   // 0..255
    const int tid = threadIdx.x;  // 0..255

    float* out_concepts = out;                          // 256*4*768 = 786432
    float* out_idx      = out + NREG * TK * DD;         // 1024
    float* out_scr      = out_idx + NREG * TK;          // 1024
    float* out_qp       = out_scr + NREG * TK;          // 256*768

    __shared__ float s_xhat[DD];
    __shared__ float s_q[KD];
    __shared__ float s_sc[512];
    __shared__ float s_red[256];
    __shared__ int   s_ri[256];
    __shared__ float s_topv[8];   // [0:4] row top, [4:8] col top
    __shared__ int   s_topi[8];
    __shared__ int   s_flat[TK];

    const float* x = registers + row * DD;

    // ---- LayerNorm (two-pass: mean, then var) ----
    float lx[3];
    float psum = 0.f;
    #pragma unroll
    for (int i = 0; i < 3; ++i) { lx[i] = x[tid + 256 * i]; psum += lx[i]; }
    s_red[tid] = psum; __syncthreads();
    for (int s = 128; s; s >>= 1) { if (tid < s) s_red[tid] += s_red[tid + s]; __syncthreads(); }
    const float mu = s_red[0] * (1.0f / DD);
    __syncthreads();
    float pvar = 0.f;
    #pragma unroll
    for (int i = 0; i < 3; ++i) { float d = lx[i] - mu; pvar += d * d; }
    s_red[tid] = pvar; __syncthreads();
    for (int s = 128; s; s >>= 1) { if (tid < s) s_red[tid] += s_red[tid + s]; __syncthreads(); }
    const float var = s_red[0] * (1.0f / DD);
    const float rstd = 1.0f / sqrtf(var + 1e-5f);
    __syncthreads();
    #pragma unroll
    for (int i = 0; i < 3; ++i) {
        int d = tid + 256 * i;
        s_xhat[d] = (lx[i] - mu) * rstd * ln_gamma[d] + ln_beta[d];
    }
    __syncthreads();

    // ---- q = xhat @ Wq + bq  (threads 0..127 each do one 768-dot) ----
    if (tid < KD) {
        float acc = bq[tid];
        for (int d = 0; d < DD; ++d)
            acc = fmaf(s_xhat[d], Wq[d * KD + tid], acc);
        s_q[tid] = acc;
    }
    __syncthreads();

    // ---- row scores + top-4 ----
    for (int t = tid; t < 512; t += 256) {
        float v = -INFINITY;
        if (t < NKEYS) {
            const float* kr = row_keys + t * HALF;
            float acc = 0.f;
            #pragma unroll 8
            for (int j = 0; j < HALF; ++j) acc = fmaf(s_q[j], kr[j], acc);
            v = acc;
        }
        s_sc[t] = v;
    }
    __syncthreads();
    for (int k = 0; k < TK; ++k) {
        float v = s_sc[tid]; int i = tid;
        float v2 = s_sc[tid + 256];
        if (v2 > v) { v = v2; i = tid + 256; }   // tie -> keep smaller idx
        s_red[tid] = v; s_ri[tid] = i; __syncthreads();
        for (int s = 128; s; s >>= 1) {
            if (tid < s) {
                float ov = s_red[tid + s]; int oi = s_ri[tid + s];
                if (ov > s_red[tid] || (ov == s_red[tid] && oi < s_ri[tid])) {
                    s_red[tid] = ov; s_ri[tid] = oi;
                }
            }
            __syncthreads();
        }
        if (tid == 0) { s_topv[k] = s_red[0]; s_topi[k] = s_ri[0]; s_sc[s_ri[0]] = -INFINITY; }
        __syncthreads();
    }

    // ---- col scores + top-4 ----
    for (int t = tid; t < 512; t += 256) {
        float v = -INFINITY;
        if (t < NKEYS) {
            const float* kc = col_keys + t * HALF;
            float acc = 0.f;
            #pragma unroll 8
            for (int j = 0; j < HALF; ++j) acc = fmaf(s_q[HALF + j], kc[j], acc);
            v = acc;
        }
        s_sc[t] = v;
    }
    __syncthreads();
    for (int k = 0; k < TK; ++k) {
        float v = s_sc[tid]; int i = tid;
        float v2 = s_sc[tid + 256];
        if (v2 > v) { v = v2; i = tid + 256; }
        s_red[tid] = v; s_ri[tid] = i; __syncthreads();
        for (int s = 128; s; s >>= 1) {
            if (tid < s) {
                float ov = s_red[tid + s]; int oi = s_ri[tid + s];
                if (ov > s_red[tid] || (ov == s_red[tid] && oi < s_ri[tid])) {
                    s_red[tid] = ov; s_ri[tid] = oi;
                }
            }
            __syncthreads();
        }
        if (tid == 0) { s_topv[4 + k] = s_red[0]; s_topi[4 + k] = s_ri[0]; s_sc[s_ri[0]] = -INFINITY; }
        __syncthreads();
    }

    // ---- merge 16 candidates -> top-4 (value desc, flat idx asc) ----
    if (tid == 0) {
        float bv[TK]; int bi[TK];
        #pragma unroll
        for (int k = 0; k < TK; ++k) { bv[k] = -INFINITY; bi[k] = 0x7fffffff; }
        for (int a = 0; a < TK; ++a) {
            for (int c = 0; c < TK; ++c) {
                float v = s_topv[a] + s_topv[4 + c];
                int idx = s_topi[a] * NKEYS + s_topi[4 + c];
                for (int k = 0; k < TK; ++k) {
                    if (v > bv[k] || (v == bv[k] && idx < bi[k])) {
                        for (int m = TK - 1; m > k; --m) { bv[m] = bv[m - 1]; bi[m] = bi[m - 1]; }
                        bv[k] = v; bi[k] = idx;
                        break;
                    }
                }
            }
        }
        #pragma unroll
        for (int k = 0; k < TK; ++k) {
            out_idx[row * TK + k] = (float)bi[k];
            out_scr[row * TK + k] = bv[k];
            s_flat[k] = bi[k];
        }
    }
    __syncthreads();

    // ---- query_projected = q @ Wqc + bqc  (coalesced across tid) ----
    #pragma unroll
    for (int i = 0; i < 3; ++i) {
        int d = tid + 256 * i;
        float acc = bqc[d];
        #pragma unroll 8
        for (int k = 0; k < KD; ++k) acc = fmaf(s_q[k], Wqc[k * DD + d], acc);
        out_qp[row * DD + d] = acc;
    }

    // ---- gather concepts ----
    for (int k = 0; k < TK; ++k) {
        const float* src = concepts + (long)s_flat[k] * DD;
        float* dst = out_concepts + (long)(row * TK + k) * DD;
        for (int d = tid; d < DD; d += 256) dst[d] = src[d];
    }
}

extern "C" void kernel_launch(void* const* d_in, const int* in_sizes, int n_in,
                              void* d_out, int out_size, void* d_ws, size_t ws_size,
                              hipStream_t stream) {
    const float* registers = (const float*)d_in[0];
    const float* row_keys  = (const float*)d_in[1];
    const float* col_keys  = (const float*)d_in[2];
    const float* concepts  = (const float*)d_in[3];
    const float* ln_gamma  = (const float*)d_in[4];
    const float* ln_beta   = (const float*)d_in[5];
    const float* Wq        = (const float*)d_in[6];
    const float* bq        = (const float*)d_in[7];
    const float* Wqc       = (const float*)d_in[8];
    const float* bqc       = (const float*)d_in[9];
    float* out = (float*)d_out;

    concept_all<<<NREG, 256, 0, stream>>>(registers, row_keys, col_keys, concepts,
                                          ln_gamma, ln_beta, Wq, bq, Wqc, bqc, out);
}